// Round 6
// baseline (165.523 us; speedup 1.0000x reference)
//
#include <hip/hip_runtime.h>
#include <hip/hip_bf16.h>

typedef __bf16 bf16;
typedef __bf16 bf16x4 __attribute__((ext_vector_type(4)));
typedef __bf16 bf16x8 __attribute__((ext_vector_type(8)));
typedef float  f32x4  __attribute__((ext_vector_type(4)));
typedef short  s16x4  __attribute__((ext_vector_type(4)));

#define DEVI __device__ __forceinline__

// B_=2048 windows, N=64 tokens, C=256, H=8 heads, HD=32, NW=64 windows/image
static constexpr float kScale = 0.17677669529663687f;  // 32^-0.5

DEVI f32x4 mfma32(bf16x8 a, bf16x8 b, f32x4 c) {
  return __builtin_amdgcn_mfma_f32_16x16x32_bf16(a, b, c, 0, 0, 0);
}
// K=16 bf16 MFMA; builtin is the "_1k" spelling; host pass falls to inline asm
// (parsed but never emitted: device-only function).
DEVI f32x4 mfma16(bf16x4 a, bf16x4 b, f32x4 c) {
#if __has_builtin(__builtin_amdgcn_mfma_f32_16x16x16bf16_1k)
  return __builtin_amdgcn_mfma_f32_16x16x16bf16_1k(
      __builtin_bit_cast(s16x4, a), __builtin_bit_cast(s16x4, b), c, 0, 0, 0);
#else
  f32x4 d;
  asm volatile("v_mfma_f32_16x16x16_bf16 %0, %1, %2, %3"
               : "=v"(d)
               : "v"(a), "v"(b), "v"(c));
  return d;
#endif
}
DEVI bf16x4 pk4(f32x4 v) {
  bf16x4 p;
  p[0] = (bf16)v[0]; p[1] = (bf16)v[1]; p[2] = (bf16)v[2]; p[3] = (bf16)v[3];
  return p;
}

// ---------------- prep ----------------
// wstream: 24 chunks (m*8 + k/32) of [256 n][32 kk] bf16 = 16 KB each.
//   Row = 64 B. Byte within row: (2*kk) ^ ((n&3)<<4)  -> fragment reads
//   (16B at (g*16)^((n&3)<<4)) are bank-conflict-free (8 lanes per bank-quad).
//   q-scale folded into m=0. wpstream: 8 chunks, same layout, for wp.
// bqkv[m][n] (q-scaled), biasM[w64][h][i][j] = bias_table[rel_index[i][j]][h]+mask.
__global__ __launch_bounds__(256) void prep_kernel(
    const float* __restrict__ wq, const float* __restrict__ bq,
    const float* __restrict__ wk, const float* __restrict__ bk,
    const float* __restrict__ wv, const float* __restrict__ bv,
    const float* __restrict__ wp,
    const float* __restrict__ bias_table, const int* __restrict__ rel_index,
    const float* __restrict__ mask,
    char* __restrict__ wstream, char* __restrict__ wpstream,
    float* __restrict__ bqkv, float* __restrict__ biasM) {
  int idx = blockIdx.x * 256 + threadIdx.x;
  if (idx < 196608) {                       // 3*256*256 qkv weights
    int m = idx >> 16, n = idx & 255, k = (idx >> 8) & 255;
    const float* w = (m == 0) ? wq : (m == 1 ? wk : wv);
    float v = w[k * 256 + n];
    if (m == 0) v *= kScale;
    *(bf16*)(wstream + (size_t)(m * 8 + (k >> 5)) * 16384 + n * 64 +
             (((k & 31) * 2) ^ ((n & 3) << 4))) = (bf16)v;
  } else if (idx < 262144) {                // + 256*256 proj weight
    int rem = idx - 196608;
    int n = rem & 255, k = (rem >> 8) & 255;
    *(bf16*)(wpstream + (size_t)(k >> 5) * 16384 + n * 64 +
             (((k & 31) * 2) ^ ((n & 3) << 4))) = (bf16)wp[k * 256 + n];
  } else if (idx < 262912) {                // + 3*256 biases
    int rem = idx - 262144;
    int m = rem >> 8, n = rem & 255;
    const float* b = (m == 0) ? bq : (m == 1 ? bk : bv);
    float v = b[n];
    if (m == 0) v *= kScale;
    bqkv[rem] = v;
  } else if (idx < 2360064) {               // + 64*8*64*64 fused bias+mask
    int rem = idx - 262912;
    int w = rem >> 15, h = (rem >> 12) & 7, ij = rem & 4095;
    biasM[rem] = bias_table[rel_index[ij] * 8 + h] + mask[w * 4096 + ij];
  }
}

// ---------------- fused swin attention block kernel ----------------
// Block = 1 window, 4 waves; wave w owns output-channel slice [64w, 64w+64)
// = heads {2w,2w+1} for all phases. Weight chunks (16 KB) double-buffered:
// per chunk: ds_read cur -> ds_write prefetched regs into other buf ->
// global-load next-next -> MFMA -> ONE barrier. Staging never sits between
// two barriers (T3-lite).
__global__ __launch_bounds__(256, 2) void swin_kernel(
    const float* __restrict__ x, const char* __restrict__ wstream,
    const char* __restrict__ wpstream, const float* __restrict__ bqkv,
    const float* __restrict__ bp, const float* __restrict__ biasM,
    float* __restrict__ out) {
  __shared__ __align__(16) char xs_ob[32768];  // xs (QKV phase), then obuf
  __shared__ __align__(16) char wbuf[32768];   // 2 x 16 KB weight chunks

  int tid = threadIdx.x;
  int w = tid >> 6, lane = tid & 63;
  int g = lane >> 4, c = lane & 15;
  // win remap: same-XCD-coresident blocks share win&63 -> biasM slice L2-hot
  int bid = blockIdx.x;
  int win = (bid & 7) * 256 + ((bid >> 3) & 3) * 64 + (bid >> 5);
  const f32x4 fz = {0.f, 0.f, 0.f, 0.f};

  // ---- stage x window -> bf16 LDS [64 t][256 k], rows 512B, XOR swz ----
  {
    const char* xw = (const char*)(x + (size_t)win * 16384);
#pragma unroll
    for (int i = 0; i < 8; ++i) {
      int gb = i * 8192 + tid * 32;
      float4 f0 = *(const float4*)(xw + gb);
      float4 f1 = *(const float4*)(xw + gb + 16);
      bf16x8 v;
      v[0] = (bf16)f0.x; v[1] = (bf16)f0.y; v[2] = (bf16)f0.z; v[3] = (bf16)f0.w;
      v[4] = (bf16)f1.x; v[5] = (bf16)f1.y; v[6] = (bf16)f1.z; v[7] = (bf16)f1.w;
      int t = gb >> 10, ir = (gb & 1023) >> 1;
      *(bf16x8*)(xs_ob + ((t * 512 + ir) ^ ((t & 7) << 4))) = v;
    }
  }
  // prologue: chunk0 -> buf0, prefetch chunk1 -> gr
  bf16x8 gr[4];
#pragma unroll
  for (int j = 0; j < 4; ++j)
    gr[j] = *(const bf16x8*)(wstream + (size_t)j * 4096 + (size_t)tid * 16);
#pragma unroll
  for (int j = 0; j < 4; ++j)
    *(bf16x8*)(wbuf + j * 4096 + tid * 16) = gr[j];
#pragma unroll
  for (int j = 0; j < 4; ++j)
    gr[j] = *(const bf16x8*)(wstream + 16384 + (size_t)j * 4096 + (size_t)tid * 16);
  __syncthreads();

  bf16x4 qp[4][4], kp[4][4], vp[4][4];
  f32x4 acc[4][4];

  // ---- QKV: 24 chunks (m = i>>3, kq = i&7), 1 barrier each ----
  for (int i = 0; i < 24; ++i) {
    int m = i >> 3, kq = i & 7;
    char* cur = wbuf + (i & 1) * 16384;
    char* nxt = wbuf + ((i + 1) & 1) * 16384;

    bf16x8 xf[4], wf[4];
#pragma unroll
    for (int tt = 0; tt < 4; ++tt)
      xf[tt] = *(const bf16x8*)(
          xs_ob + (((tt * 16 + c) * 512 + kq * 64 + g * 16) ^ ((c & 7) << 4)));
#pragma unroll
    for (int nt = 0; nt < 4; ++nt)
      wf[nt] = *(const bf16x8*)(
          cur + (w * 64 + nt * 16 + c) * 64 + ((g * 16) ^ ((c & 3) << 4)));

    // stage: write chunk i+1, load chunk i+2
#pragma unroll
    for (int j = 0; j < 4; ++j)
      *(bf16x8*)(nxt + j * 4096 + tid * 16) = gr[j];
    {
      const char* src = (i < 22) ? (wstream + (size_t)(i + 2) * 16384)
                                 : (wpstream + (size_t)(i - 22) * 16384);
#pragma unroll
      for (int j = 0; j < 4; ++j)
        gr[j] = *(const bf16x8*)(src + (size_t)j * 4096 + (size_t)tid * 16);
    }

    if (kq == 0) {
      if (m < 2) {
#pragma unroll
        for (int nt = 0; nt < 4; ++nt) {
          f32x4 b4 = *(const f32x4*)(bqkv + m * 256 + w * 64 + nt * 16 + g * 4);
#pragma unroll
          for (int tt = 0; tt < 4; ++tt) acc[tt][nt] = b4;
        }
      } else {
#pragma unroll
        for (int nt = 0; nt < 4; ++nt) {
          float bv_ = bqkv[512 + w * 64 + nt * 16 + c];
          f32x4 b4 = {bv_, bv_, bv_, bv_};
#pragma unroll
          for (int tt = 0; tt < 4; ++tt) acc[tt][nt] = b4;
        }
      }
    }
    if (m < 2) {
#pragma unroll
      for (int tt = 0; tt < 4; ++tt)
#pragma unroll
        for (int nt = 0; nt < 4; ++nt)
          acc[tt][nt] = mfma32(wf[nt], xf[tt], acc[tt][nt]);
    } else {
#pragma unroll
      for (int tt = 0; tt < 4; ++tt)
#pragma unroll
        for (int nt = 0; nt < 4; ++nt)
          acc[tt][nt] = mfma32(xf[tt], wf[nt], acc[tt][nt]);
    }
    if (kq == 7) {
#pragma unroll
      for (int tt = 0; tt < 4; ++tt)
#pragma unroll
        for (int nt = 0; nt < 4; ++nt) {
          if (m == 0)      qp[tt][nt] = pk4(acc[tt][nt]);
          else if (m == 1) kp[tt][nt] = pk4(acc[tt][nt]);
          else             vp[tt][nt] = pk4(acc[tt][nt]);
        }
    }
    __syncthreads();
  }
  // buf0 = wp chunk 0 (written at i=23), gr = wp chunk 1. xs reads all done.

  // ---- attention: fully in-register ----
#pragma unroll
  for (int hh = 0; hh < 2; ++hh) {
    int h = w * 2 + hh;
    const float* bm = biasM + ((size_t)(win & 63) * 8 + h) * 4096;
#pragma unroll
    for (int mi = 0; mi < 4; ++mi) {
      f32x4 s[4];
#pragma unroll
      for (int mj = 0; mj < 4; ++mj)
        s[mj] = *(const f32x4*)(bm + (mi * 16 + c) * 64 + mj * 16 + g * 4);
#pragma unroll
      for (int dd = 0; dd < 2; ++dd)
#pragma unroll
        for (int mj = 0; mj < 4; ++mj)
          s[mj] = mfma16(kp[mj][hh * 2 + dd], qp[mi][hh * 2 + dd], s[mj]);
      float mx;
      {
        f32x4 m4 = s[0];
#pragma unroll
        for (int mj = 1; mj < 4; ++mj) {
          m4[0] = fmaxf(m4[0], s[mj][0]); m4[1] = fmaxf(m4[1], s[mj][1]);
          m4[2] = fmaxf(m4[2], s[mj][2]); m4[3] = fmaxf(m4[3], s[mj][3]);
        }
        mx = fmaxf(fmaxf(m4[0], m4[1]), fmaxf(m4[2], m4[3]));
        mx = fmaxf(mx, __shfl_xor(mx, 16));
        mx = fmaxf(mx, __shfl_xor(mx, 32));
      }
      float sum;
      {
        f32x4 s4 = fz;
#pragma unroll
        for (int mj = 0; mj < 4; ++mj) {
#pragma unroll
          for (int r = 0; r < 4; ++r) s[mj][r] = __expf(s[mj][r] - mx);
          s4 += s[mj];
        }
        sum = (s4[0] + s4[1]) + (s4[2] + s4[3]);
        sum += __shfl_xor(sum, 16);
        sum += __shfl_xor(sum, 32);
      }
      float rs = 1.0f / sum;
      bf16x4 pf[4];
#pragma unroll
      for (int mj = 0; mj < 4; ++mj) pf[mj] = pk4(s[mj]);
#pragma unroll
      for (int dt = 0; dt < 2; ++dt) {
        f32x4 o = fz;
#pragma unroll
        for (int mj = 0; mj < 4; ++mj)
          o = mfma16(vp[mj][hh * 2 + dt], pf[mj], o);
        bf16x4 ov;
        ov[0] = (bf16)(o[0] * rs); ov[1] = (bf16)(o[1] * rs);
        ov[2] = (bf16)(o[2] * rs); ov[3] = (bf16)(o[3] * rs);
        *(bf16x4*)(xs_ob + (((mi * 16 + c) * 512 + (h * 32 + dt * 16 + g * 4) * 2) ^
                            ((c & 7) << 4))) = ov;
      }
    }
  }
  __syncthreads();  // obuf visible to all waves

  // ---- projection: 8 chunks (i = 24..31), same dbuf pattern ----
  f32x4 acc2[4][4];
#pragma unroll
  for (int nt = 0; nt < 4; ++nt) {
    f32x4 b4 = *(const f32x4*)(bp + w * 64 + nt * 16 + g * 4);
#pragma unroll
    for (int tt = 0; tt < 4; ++tt) acc2[tt][nt] = b4;
  }
  for (int i = 24; i < 32; ++i) {
    int cc = i - 24;
    char* cur = wbuf + (i & 1) * 16384;
    char* nxt = wbuf + ((i + 1) & 1) * 16384;

    bf16x8 of[4], wf[4];
#pragma unroll
    for (int tt = 0; tt < 4; ++tt)
      of[tt] = *(const bf16x8*)(
          xs_ob + (((tt * 16 + c) * 512 + cc * 64 + g * 16) ^ ((c & 7) << 4)));
#pragma unroll
    for (int nt = 0; nt < 4; ++nt)
      wf[nt] = *(const bf16x8*)(
          cur + (w * 64 + nt * 16 + c) * 64 + ((g * 16) ^ ((c & 3) << 4)));

    if (i <= 30) {
#pragma unroll
      for (int j = 0; j < 4; ++j)
        *(bf16x8*)(nxt + j * 4096 + tid * 16) = gr[j];
      if (i <= 29) {
#pragma unroll
        for (int j = 0; j < 4; ++j)
          gr[j] = *(const bf16x8*)(wpstream + (size_t)(i - 22) * 16384 +
                                   (size_t)j * 4096 + (size_t)tid * 16);
      }
    }
#pragma unroll
    for (int tt = 0; tt < 4; ++tt)
#pragma unroll
      for (int nt = 0; nt < 4; ++nt)
        acc2[tt][nt] = mfma32(wf[nt], of[tt], acc2[tt][nt]);
    if (i < 31) __syncthreads();
  }
  // store: C[n][t] -> out[win*64 + t][n], f32x4 along n
#pragma unroll
  for (int tt = 0; tt < 4; ++tt)
#pragma unroll
    for (int nt = 0; nt < 4; ++nt)
      *(f32x4*)(out + ((size_t)win * 64 + tt * 16 + c) * 256 + w * 64 + nt * 16 + g * 4) =
          acc2[tt][nt];
}

extern "C" void kernel_launch(void* const* d_in, const int* in_sizes, int n_in,
                              void* d_out, int out_size, void* d_ws, size_t ws_size,
                              hipStream_t stream) {
  const float* x          = (const float*)d_in[0];
  const float* mask       = (const float*)d_in[1];
  const float* wq         = (const float*)d_in[2];
  const float* bq         = (const float*)d_in[3];
  const float* wk         = (const float*)d_in[4];
  const float* bk         = (const float*)d_in[5];
  const float* wv         = (const float*)d_in[6];
  const float* bv         = (const float*)d_in[7];
  const float* wp         = (const float*)d_in[8];
  const float* bp         = (const float*)d_in[9];
  const float* bias_table = (const float*)d_in[10];
  const int*   rel_index  = (const int*)d_in[11];

  // Workspace (~8.9 MB): wstream | wpstream | bqkv | biasM
  char* ws = (char*)d_ws;
  size_t o = 0;
  char* wstream = ws + o;  o += (size_t)24 * 16384;
  char* wpstream = ws + o; o += (size_t)8 * 16384;
  float* bqkv = (float*)(ws + o); o += (size_t)768 * 4;
  float* biasM = (float*)(ws + o); o += (size_t)64 * 8 * 64 * 64 * 4;
  if (ws_size < o) return;

  prep_kernel<<<9219, 256, 0, stream>>>(wq, bq, wk, bk, wv, bv, wp,
                                        bias_table, rel_index, mask,
                                        wstream, wpstream, bqkv, biasM);
  swin_kernel<<<2048, 256, 0, stream>>>(x, wstream, wpstream, bqkv, bp, biasM,
                                        (float*)d_out);
}